// Round 2
// baseline (9934.717 us; speedup 1.0000x reference)
//
#include <hip/hip_runtime.h>
#include <stdint.h>

// B=64, T=128, D=512. Scan kernel: 16 persistent blocks x 512 threads,
// column-partitioned ownership (32 cols/block per layer), 2 grid barriers/step.
// R2: no threadfence (was buffer_wbl2+inv -> 6MB/step HBM flush). Cross-block
// buffers (Rc, dout_rm, W2T, lossAcc) use agent-scope relaxed atomics (sc0 sc1:
// write-through stores, cache-bypassing loads). Private state stays plain/L2.

typedef __attribute__((ext_vector_type(8))) short short8;
typedef __attribute__((ext_vector_type(4))) float floatx4;

#define GBLK 16
#define SC_AGENT __HIP_MEMORY_SCOPE_AGENT

__device__ inline floatx4 mfma_bf16(short8 a, short8 b, floatx4 c) {
  return __builtin_amdgcn_mfma_f32_16x16x32_bf16(a, b, c, 0, 0, 0);
}

__device__ inline unsigned short f2bf(float f) {
  unsigned u = __float_as_uint(f);
  u += 0x7fffu + ((u >> 16) & 1u);
  return (unsigned short)(u >> 16);
}
__device__ inline float bf2f(unsigned short h) {
  return __uint_as_float(((unsigned)h) << 16);
}
__device__ inline short8 ldbf8(const unsigned short* p) {
  return *reinterpret_cast<const short8*>(p);
}
// agent-coherent (sc0 sc1) accessors for cross-block buffers
__device__ inline void st2_sc(unsigned short* p, unsigned short v) {
  __hip_atomic_store(p, v, __ATOMIC_RELAXED, SC_AGENT);
}
__device__ inline void st8_sc(unsigned short* p, unsigned long long v) {
  __hip_atomic_store(reinterpret_cast<unsigned long long*>(p), v,
                     __ATOMIC_RELAXED, SC_AGENT);
}
__device__ inline short8 ld16_sc(const unsigned short* p) {
  union { unsigned long long u[2]; short8 s; } c;
  c.u[0] = __hip_atomic_load(reinterpret_cast<const unsigned long long*>(p),
                             __ATOMIC_RELAXED, SC_AGENT);
  c.u[1] = __hip_atomic_load(reinterpret_cast<const unsigned long long*>(p + 4),
                             __ATOMIC_RELAXED, SC_AGENT);
  return c.s;
}
__device__ inline short8 pack8(const float* p) {
  float4 a = *reinterpret_cast<const float4*>(p);
  float4 b = *reinterpret_cast<const float4*>(p + 4);
  short8 r;
  r[0] = (short)f2bf(a.x); r[1] = (short)f2bf(a.y);
  r[2] = (short)f2bf(a.z); r[3] = (short)f2bf(a.w);
  r[4] = (short)f2bf(b.x); r[5] = (short)f2bf(b.y);
  r[6] = (short)f2bf(b.z); r[7] = (short)f2bf(b.w);
  return r;
}

// Grid barrier WITHOUT cache maintenance. __syncthreads drains each wave's
// vmcnt (sc1 stores are agent-visible at vmcnt retire); arrival/spins are
// relaxed agent atomics. No wbL2, no inv.
__device__ inline void gridbar(unsigned* ctr, unsigned& ep) {
  __syncthreads();
  if (threadIdx.x == 0) {
    asm volatile("s_waitcnt vmcnt(0)" ::: "memory");
    __hip_atomic_fetch_add(ctr, 1u, __ATOMIC_RELAXED, SC_AGENT);
    const unsigned target = (ep + 1u) * GBLK;
    while (__hip_atomic_load(ctr, __ATOMIC_RELAXED, SC_AGENT) < target)
      __builtin_amdgcn_s_sleep(1);
  }
  ++ep;
  __syncthreads();
}

// ---------------- q/k/v projections (bf16 out) ----------------
__global__ __launch_bounds__(256) void qkv_kernel(
    const float* __restrict__ x, const float* __restrict__ WQ,
    const float* __restrict__ WK, const float* __restrict__ WV,
    unsigned short* __restrict__ qb, unsigned short* __restrict__ kb,
    unsigned short* __restrict__ vb, unsigned short* __restrict__ kbT) {
  const int tid = threadIdx.x;
  const int lane = tid & 63, w = tid >> 6;
  const int quad = lane >> 4, l16 = lane & 15;
  const int Mbase = blockIdx.x * 128;
  const int Nbase = blockIdx.y * 128;
  const int z = blockIdx.z;
  const float* W = (z == 0) ? WQ : (z == 1) ? WK : WV;
  unsigned short* dst = (z == 0) ? qb : (z == 1) ? kb : vb;

  floatx4 acc[2][8];
  for (int a = 0; a < 2; ++a)
    for (int n = 0; n < 8; ++n) acc[a][n] = (floatx4){0.f, 0.f, 0.f, 0.f};

  const int r0 = Mbase + w * 32 + l16;
  for (int ks = 0; ks < 16; ++ks) {
    const int k0 = ks * 32 + quad * 8;
    short8 a0 = pack8(x + (size_t)r0 * 512 + k0);
    short8 a1 = pack8(x + (size_t)(r0 + 16) * 512 + k0);
    for (int n = 0; n < 8; ++n) {
      short8 b = pack8(W + (size_t)(Nbase + n * 16 + l16) * 512 + k0);
      acc[0][n] = mfma_bf16(a0, b, acc[0][n]);
      acc[1][n] = mfma_bf16(a1, b, acc[1][n]);
    }
  }
  for (int tm = 0; tm < 2; ++tm)
    for (int n = 0; n < 8; ++n)
      for (int rr = 0; rr < 4; ++rr) {
        int row = Mbase + w * 32 + tm * 16 + quad * 4 + rr;  // b*T + t
        int col = Nbase + n * 16 + l16;
        int b = row >> 7, t = row & 127;
        unsigned short val = f2bf(acc[tm][n][rr]);
        dst[((size_t)(t * 64 + b) << 9) + col] = val;
        if (z == 1) kbT[((size_t)(t * 512 + col) << 6) + b] = val;  // k^T per t
      }
}

// ---------------- per-step scalar gates + control init ----------------
__global__ __launch_bounds__(256) void gates_kernel(
    const float* __restrict__ x,
    const float* __restrict__ tw, const float* __restrict__ tb,
    const float* __restrict__ ew, const float* __restrict__ eb,
    const float* __restrict__ aw, const float* __restrict__ ab,
    float* __restrict__ gates, float* __restrict__ lossAcc,
    unsigned* __restrict__ ctr) {
  const int t = blockIdx.x, tid = threadIdx.x;
  __shared__ float red[192];
  if (tid < 192) {
    int g = tid >> 6, b = tid & 63;
    const float* wr = (g == 0) ? tw : (g == 1) ? ew : aw;
    float bias = (g == 0) ? tb[0] : (g == 1) ? eb[0] : ab[0];
    const float* xr = x + ((size_t)b * 128 + t) * 512;
    float s = 0.f;
    for (int i = 0; i < 512; i += 4) {
      float4 xv = *reinterpret_cast<const float4*>(xr + i);
      float4 wv = *reinterpret_cast<const float4*>(wr + i);
      s += xv.x * wv.x + xv.y * wv.y + xv.z * wv.z + xv.w * wv.w;
    }
    red[tid] = 1.f / (1.f + expf(-(s + bias)));
  }
  if (tid == 192) lossAcc[t] = 0.f;
  if (tid == 193 && t == 0) *ctr = 0u;
  __syncthreads();
  if (tid < 3) {
    float s = 0.f;
    for (int i = 0; i < 64; ++i) s += red[tid * 64 + i];
    gates[tid * 128 + t] = s * (1.f / 64.f);
  }
}

// ---------------- persistent sequential scan ----------------
__global__ __launch_bounds__(512, 1) void scan_kernel(
    const unsigned short* __restrict__ qb, const unsigned short* __restrict__ kb,
    const unsigned short* __restrict__ vb, const unsigned short* __restrict__ kbT,
    const float* __restrict__ gates, float* lossAcc, unsigned* ctr,
    const float* __restrict__ inW1, const float* __restrict__ inb1,
    const float* __restrict__ inW2, const float* __restrict__ inb2,
    float* W1ws, float* M1w, float* b1ws, float* M1b,
    float* W2ws, float* M2w, float* b2ws, float* M2b,
    unsigned short* W1bf, unsigned short* W2bf, unsigned short* W2T,
    unsigned short* Rbuf, unsigned short* hT,
    unsigned short* dout_rm, unsigned short* dout_t, unsigned short* dpreT,
    float* __restrict__ out) {
  const int tid = threadIdx.x, bid = blockIdx.x;
  const int lane = tid & 63, w = tid >> 6;
  const int quad = lane >> 4, l16 = lane & 15;
  const int J = bid * 32;  // owned column base, both layers
  unsigned ep = 0;

  // init owned state from inputs (ws is poisoned every launch)
  for (int c = 0; c < 32; ++c) {
    int idx = c * 512 + tid;
    int r = idx >> 9, col = idx & 511;
    size_t g = (size_t)(J + r) * 512 + col;
    float w1 = inW1[g]; W1ws[g] = w1; M1w[g] = 0.f; W1bf[g] = f2bf(w1);
    float w2 = inW2[g]; W2ws[g] = w2; M2w[g] = 0.f; W2bf[g] = f2bf(w2);
  }
  if (tid < 32) {
    b1ws[J + tid] = inb1[J + tid]; M1b[J + tid] = 0.f;
    b2ws[J + tid] = inb2[J + tid]; M2b[J + tid] = 0.f;
  }
  {  // publish W2^T buffer 0 (bf16, agent-coherent), own column slice of rows
    int j = tid;
    unsigned short tmp[32];
    for (int mm = 0; mm < 32; ++mm) tmp[mm] = f2bf(inW2[(size_t)(J + mm) * 512 + j]);
    for (int s = 0; s < 8; ++s) {
      const unsigned short* tp = tmp + s * 4;
      unsigned long long v = (unsigned long long)tp[0] |
                             ((unsigned long long)tp[1] << 16) |
                             ((unsigned long long)tp[2] << 32) |
                             ((unsigned long long)tp[3] << 48);
      st8_sc(W2T + (size_t)j * 512 + J + s * 4, v);
    }
  }
  __syncthreads();

  for (int t = 0; t < 128; ++t) {
    const int par = t & 1, nxt = par ^ 1;
    const float th = gates[t], et = gates[128 + t], al = gates[256 + t];
    const unsigned short* qt = qb + ((size_t)t << 15);
    const unsigned short* kt = kb + ((size_t)t << 15);
    const unsigned short* vt = vb + ((size_t)t << 15);
    const unsigned short* ktT = kbT + ((size_t)t << 15);
    unsigned short* Rc = Rbuf + par * 65536;   // [128][512] relu([q;k]@W1^T+b1)
    unsigned short* hTc = hT + par * 32768;    // [512][64] h^T (private)

    // ---- Phase A: layer-1 forward, own 32 cols, rows = [q_t; k_t] ----
    {
      const int row = w * 16 + l16;
      const unsigned short* arow = (row < 64) ? (qt + (size_t)row * 512)
                                              : (kt + (size_t)(row - 64) * 512);
      floatx4 a0 = {0.f,0.f,0.f,0.f}, a1 = {0.f,0.f,0.f,0.f};
      for (int ks = 0; ks < 16; ++ks) {
        int k0 = ks * 32 + quad * 8;
        short8 af = ldbf8(arow + k0);
        short8 b0 = ldbf8(W1bf + (size_t)(J + l16) * 512 + k0);
        short8 b1f = ldbf8(W1bf + (size_t)(J + 16 + l16) * 512 + k0);
        a0 = mfma_bf16(af, b0, a0);
        a1 = mfma_bf16(af, b1f, a1);
      }
      float bi0 = b1ws[J + l16], bi1 = b1ws[J + 16 + l16];
      for (int rr = 0; rr < 4; ++rr) {
        int orow = w * 16 + quad * 4 + rr;
        float v0 = fmaxf(a0[rr] + bi0, 0.f);
        float v1 = fmaxf(a1[rr] + bi1, 0.f);
        unsigned short h0 = f2bf(v0), h1 = f2bf(v1);
        st2_sc(Rc + (size_t)orow * 512 + J + l16, h0);
        st2_sc(Rc + (size_t)orow * 512 + J + 16 + l16, h1);
        if (orow >= 64) {
          hTc[(size_t)(J + l16) * 64 + (orow - 64)] = h0;
          hTc[(size_t)(J + 16 + l16) * 64 + (orow - 64)] = h1;
        }
      }
    }
    gridbar(ctr, ep);

    // ---- Phase B: layer-2 forward; mem out (rows<64), dout (rows>=64) ----
    {
      const int row = w * 16 + l16;
      const unsigned short* arow = Rc + (size_t)row * 512;
      floatx4 a0 = {0.f,0.f,0.f,0.f}, a1 = {0.f,0.f,0.f,0.f};
      for (int ks = 0; ks < 16; ++ks) {
        int k0 = ks * 32 + quad * 8;
        short8 af = ld16_sc(arow + k0);
        short8 b0 = ldbf8(W2bf + (size_t)(J + l16) * 512 + k0);
        short8 b1f = ldbf8(W2bf + (size_t)(J + 16 + l16) * 512 + k0);
        a0 = mfma_bf16(af, b0, a0);
        a1 = mfma_bf16(af, b1f, a1);
      }
      float bi0 = b2ws[J + l16], bi1 = b2ws[J + 16 + l16];
      float lossp = 0.f;
      for (int rr = 0; rr < 4; ++rr) {
        int orow = w * 16 + quad * 4 + rr;
        float o0 = a0[rr] + bi0, o1 = a1[rr] + bi1;
        if (orow < 64) {
          size_t o = ((size_t)orow * 128 + t) * 512;
          out[o + J + l16] = o0;
          out[o + J + 16 + l16] = o1;
          out[4194304 + o + J + l16] = o0;
          out[4194304 + o + J + 16 + l16] = o1;
        } else {
          int i = orow - 64;
          float d0 = o0 - bf2f(vt[(size_t)i * 512 + J + l16]);
          float d1 = o1 - bf2f(vt[(size_t)i * 512 + J + 16 + l16]);
          lossp += d0 * d0 + d1 * d1;
          unsigned short q0 = f2bf(6.103515625e-5f * d0);  // (2/N)*diff, N=32768
          unsigned short q1 = f2bf(6.103515625e-5f * d1);
          st2_sc(dout_rm + (size_t)i * 512 + J + l16, q0);
          st2_sc(dout_rm + (size_t)i * 512 + J + 16 + l16, q1);
          dout_t[(size_t)(J + l16) * 64 + i] = q0;
          dout_t[(size_t)(J + 16 + l16) * 64 + i] = q1;
        }
      }
      if (w >= 4) {
        for (int off = 32; off > 0; off >>= 1) lossp += __shfl_down(lossp, off);
        if (lane == 0)
          __hip_atomic_fetch_add(lossAcc + t, lossp, __ATOMIC_RELAXED, SC_AGENT);
      }
    }
    gridbar(ctr, ep);

    const float loss =
        __hip_atomic_load(lossAcc + t, __ATOMIC_RELAXED, SC_AGENT) * (1.f / 32768.f);
    const float pt = (loss >= 1e-10f && loss <= 1e10f) ? 1.f : 0.f;

    // ---- Phase C: dpre[:,J] = relu'(hpre) * (dout @ W2)[:,J] ----
    {
      const int mt = w & 3, nt = w >> 2;
      const int irow = mt * 16 + l16;
      const unsigned short* arow = dout_rm + (size_t)irow * 512;
      const unsigned short* w2t = W2T + (size_t)par * 262144;
      floatx4 acc = {0.f,0.f,0.f,0.f};
      for (int ks = 0; ks < 16; ++ks) {
        int k0 = ks * 32 + quad * 8;
        short8 af = ld16_sc(arow + k0);
        short8 bf = ld16_sc(w2t + (size_t)(J + nt * 16 + l16) * 512 + k0);
        acc = mfma_bf16(af, bf, acc);
      }
      for (int rr = 0; rr < 4; ++rr) {
        int i = mt * 16 + quad * 4 + rr;
        int j = J + nt * 16 + l16;
        unsigned short hb = hTc[(size_t)j * 64 + i];  // private h>0 <=> hpre>0
        float val = (hb != 0) ? acc[rr] : 0.f;
        dpreT[(size_t)j * 64 + i] = f2bf(val);
      }
    }
    __syncthreads();

    // ---- Phase D1: gW1 rows J (K=64) + momentum/decay update ----
    {
      const int mt = w & 1, ng = w >> 1;
      floatx4 acc[8];
      for (int g = 0; g < 8; ++g) acc[g] = (floatx4){0.f,0.f,0.f,0.f};
      for (int ks = 0; ks < 2; ++ks) {
        int i0 = ks * 32 + quad * 8;
        short8 af = ldbf8(dpreT + (size_t)(J + mt * 16 + l16) * 64 + i0);
        for (int g = 0; g < 8; ++g) {
          int l = (ng * 8 + g) * 16 + l16;
          short8 bf = ldbf8(ktT + (size_t)l * 64 + i0);
          acc[g] = mfma_bf16(af, bf, acc[g]);
        }
      }
      for (int g = 0; g < 8; ++g)
        for (int rr = 0; rr < 4; ++rr) {
          int jl = mt * 16 + quad * 4 + rr;
          int l = (ng * 8 + g) * 16 + l16;
          size_t idx = (size_t)(J + jl) * 512 + l;
          float gv = pt * acc[g][rr];
          float m = et * M1w[idx] - th * gv;
          float wv = (1.f - al) * W1ws[idx] + m;
          M1w[idx] = m; W1ws[idx] = wv; W1bf[idx] = f2bf(wv);
        }
      if (tid < 32) {
        float s = 0.f;
        for (int i = 0; i < 64; ++i) s += bf2f(dpreT[(size_t)(J + tid) * 64 + i]);
        float m = et * M1b[J + tid] - th * (pt * s);
        float bv = (1.f - al) * b1ws[J + tid] + m;
        M1b[J + tid] = m; b1ws[J + tid] = bv;
      }
    }

    // ---- Phase D2: gW2 rows J (K=64) + update ----
    {
      const int mt = w & 1, ng = w >> 1;
      floatx4 acc[8];
      for (int g = 0; g < 8; ++g) acc[g] = (floatx4){0.f,0.f,0.f,0.f};
      for (int ks = 0; ks < 2; ++ks) {
        int i0 = ks * 32 + quad * 8;
        short8 af = ldbf8(dout_t + (size_t)(J + mt * 16 + l16) * 64 + i0);
        for (int g = 0; g < 8; ++g) {
          int l = (ng * 8 + g) * 16 + l16;
          short8 bf = ldbf8(hTc + (size_t)l * 64 + i0);
          acc[g] = mfma_bf16(af, bf, acc[g]);
        }
      }
      for (int g = 0; g < 8; ++g)
        for (int rr = 0; rr < 4; ++rr) {
          int jl = mt * 16 + quad * 4 + rr;
          int l = (ng * 8 + g) * 16 + l16;
          size_t idx = (size_t)(J + jl) * 512 + l;
          float gv = pt * acc[g][rr];
          float m = et * M2w[idx] - th * gv;
          float wv = (1.f - al) * W2ws[idx] + m;
          M2w[idx] = m; W2ws[idx] = wv; W2bf[idx] = f2bf(wv);
        }
      if (tid < 32) {
        float s = 0.f;
        for (int i = 0; i < 64; ++i) s += bf2f(dout_t[(size_t)(J + tid) * 64 + i]);
        float m = et * M2b[J + tid] - th * (pt * s);
        float bv = (1.f - al) * b2ws[J + tid] + m;
        M2b[J + tid] = m; b2ws[J + tid] = bv;
      }
    }
    __syncthreads();

    // publish W2^T (next parity, agent-coherent) from updated own rows
    {
      int j = tid;
      unsigned short tmp[32];
      for (int mm = 0; mm < 32; ++mm) tmp[mm] = W2bf[(size_t)(J + mm) * 512 + j];
      unsigned short* dstp = W2T + (size_t)nxt * 262144 + (size_t)j * 512 + J;
      for (int s = 0; s < 8; ++s) {
        const unsigned short* tp = tmp + s * 4;
        unsigned long long v = (unsigned long long)tp[0] |
                               ((unsigned long long)tp[1] << 16) |
                               ((unsigned long long)tp[2] << 32) |
                               ((unsigned long long)tp[3] << 48);
        st8_sc(dstp + s * 4, v);
      }
    }
    __syncthreads();
  }
}

extern "C" void kernel_launch(void* const* d_in, const int* in_sizes, int n_in,
                              void* d_out, int out_size, void* d_ws, size_t ws_size,
                              hipStream_t stream) {
  const float* x  = (const float*)d_in[0];
  const float* WQ = (const float*)d_in[1];
  const float* WK = (const float*)d_in[2];
  const float* WV = (const float*)d_in[3];
  const float* tw = (const float*)d_in[4];
  const float* tb = (const float*)d_in[5];
  const float* ew = (const float*)d_in[6];
  const float* eb = (const float*)d_in[7];
  const float* aw = (const float*)d_in[8];
  const float* ab = (const float*)d_in[9];
  const float* W1 = (const float*)d_in[10];
  const float* b1 = (const float*)d_in[11];
  const float* W2 = (const float*)d_in[12];
  const float* b2 = (const float*)d_in[13];
  float* out = (float*)d_out;

  char* ws = (char*)d_ws;
  size_t off = 0;
  auto alloc = [&](size_t b) {
    char* p = ws + off;
    off = (off + b + 255) & ~(size_t)255;
    return p;
  };
  unsigned short* qb   = (unsigned short*)alloc(8388608);
  unsigned short* kb   = (unsigned short*)alloc(8388608);
  unsigned short* vb   = (unsigned short*)alloc(8388608);
  unsigned short* kbT  = (unsigned short*)alloc(8388608);
  float* gates   = (float*)alloc(1536);
  float* lossAcc = (float*)alloc(512);
  unsigned* ctr  = (unsigned*)alloc(256);
  float* W1ws = (float*)alloc(1048576);
  float* M1w  = (float*)alloc(1048576);
  float* W2ws = (float*)alloc(1048576);
  float* M2w  = (float*)alloc(1048576);
  float* b1ws = (float*)alloc(2048);
  float* M1b  = (float*)alloc(2048);
  float* b2ws = (float*)alloc(2048);
  float* M2b  = (float*)alloc(2048);
  unsigned short* W1bf = (unsigned short*)alloc(524288);
  unsigned short* W2bf = (unsigned short*)alloc(524288);
  unsigned short* W2T  = (unsigned short*)alloc(1048576);
  unsigned short* Rbuf = (unsigned short*)alloc(262144);
  unsigned short* hT   = (unsigned short*)alloc(131072);
  unsigned short* dout_rm = (unsigned short*)alloc(65536);
  unsigned short* dout_t  = (unsigned short*)alloc(65536);
  unsigned short* dpreT   = (unsigned short*)alloc(65536);
  (void)in_sizes; (void)n_in; (void)out_size; (void)ws_size;

  qkv_kernel<<<dim3(64, 4, 3), 256, 0, stream>>>(x, WQ, WK, WV, qb, kb, vb, kbT);
  gates_kernel<<<dim3(128), 256, 0, stream>>>(x, tw, tb, ew, eb, aw, ab,
                                              gates, lossAcc, ctr);
  scan_kernel<<<dim3(GBLK), 512, 0, stream>>>(
      qb, kb, vb, kbT, gates, lossAcc, ctr,
      W1, b1, W2, b2,
      W1ws, M1w, b1ws, M1b, W2ws, M2w, b2ws, M2b,
      W1bf, W2bf, W2T, Rbuf, hT, dout_rm, dout_t, dpreT, out);
}

// Round 3
// 7755.949 us; speedup vs baseline: 1.2809x; 1.2809x over previous
//
#include <hip/hip_runtime.h>
#include <stdint.h>

// B=64, T=128, D=512. Persistent scan: 16 blocks x 512 threads, column-
// partitioned (32 rows of W1 and W2 per block), 2 grid barriers/step.
// R3: fp32 masters+momentum live in REGISTERS (frag-layout aligned);
// bf16 W1/W2 copies + local transposes live in LDS; cross-block buffers
// (Rc, hT, dout, W2T) use agent-scope relaxed atomics with MANUALLY HOISTED
// fragment loads (batch of independent loads, then MFMA chain).

typedef __attribute__((ext_vector_type(8))) short short8;
typedef __attribute__((ext_vector_type(4))) float floatx4;

#define GBLK 16
#define SC_AGENT __HIP_MEMORY_SCOPE_AGENT

__device__ inline floatx4 mfma_bf16(short8 a, short8 b, floatx4 c) {
  return __builtin_amdgcn_mfma_f32_16x16x32_bf16(a, b, c, 0, 0, 0);
}
__device__ inline unsigned short f2bf(float f) {
  unsigned u = __float_as_uint(f);
  u += 0x7fffu + ((u >> 16) & 1u);
  return (unsigned short)(u >> 16);
}
__device__ inline float bf2f(unsigned short h) {
  return __uint_as_float(((unsigned)h) << 16);
}
__device__ inline short8 ldbf8(const unsigned short* p) {
  return *reinterpret_cast<const short8*>(p);
}
__device__ inline void st2_sc(unsigned short* p, unsigned short v) {
  __hip_atomic_store(p, v, __ATOMIC_RELAXED, SC_AGENT);
}
__device__ inline void st8_sc(unsigned short* p, unsigned long long v) {
  __hip_atomic_store(reinterpret_cast<unsigned long long*>(p), v,
                     __ATOMIC_RELAXED, SC_AGENT);
}
__device__ inline short8 ld16_sc(const unsigned short* p) {
  union { unsigned long long u[2]; short8 s; } c;
  c.u[0] = __hip_atomic_load(reinterpret_cast<const unsigned long long*>(p),
                             __ATOMIC_RELAXED, SC_AGENT);
  c.u[1] = __hip_atomic_load(reinterpret_cast<const unsigned long long*>(p + 4),
                             __ATOMIC_RELAXED, SC_AGENT);
  return c.s;
}
__device__ inline unsigned long long pack4(const unsigned short* p) {
  return (unsigned long long)p[0] | ((unsigned long long)p[1] << 16) |
         ((unsigned long long)p[2] << 32) | ((unsigned long long)p[3] << 48);
}
__device__ inline short8 pack8(const float* p) {
  float4 a = *reinterpret_cast<const float4*>(p);
  float4 b = *reinterpret_cast<const float4*>(p + 4);
  short8 r;
  r[0] = (short)f2bf(a.x); r[1] = (short)f2bf(a.y);
  r[2] = (short)f2bf(a.z); r[3] = (short)f2bf(a.w);
  r[4] = (short)f2bf(b.x); r[5] = (short)f2bf(b.y);
  r[6] = (short)f2bf(b.z); r[7] = (short)f2bf(b.w);
  return r;
}

__device__ inline void gridbar(unsigned* ctr, unsigned& ep) {
  __syncthreads();  // drains each wave's vmcnt before s_barrier
  if (threadIdx.x == 0) {
    __hip_atomic_fetch_add(ctr, 1u, __ATOMIC_RELAXED, SC_AGENT);
    const unsigned target = (ep + 1u) * GBLK;
    while (__hip_atomic_load(ctr, __ATOMIC_RELAXED, SC_AGENT) < target)
      __builtin_amdgcn_s_sleep(1);
  }
  ++ep;
  __syncthreads();
}

// ---------------- q/k/v projections (bf16 out) ----------------
__global__ __launch_bounds__(256) void qkv_kernel(
    const float* __restrict__ x, const float* __restrict__ WQ,
    const float* __restrict__ WK, const float* __restrict__ WV,
    unsigned short* __restrict__ qb, unsigned short* __restrict__ kb,
    unsigned short* __restrict__ vb, unsigned short* __restrict__ kbT) {
  const int tid = threadIdx.x;
  const int lane = tid & 63, w = tid >> 6;
  const int quad = lane >> 4, l16 = lane & 15;
  const int Mbase = blockIdx.x * 128;
  const int Nbase = blockIdx.y * 128;
  const int z = blockIdx.z;
  const float* W = (z == 0) ? WQ : (z == 1) ? WK : WV;
  unsigned short* dst = (z == 0) ? qb : (z == 1) ? kb : vb;

  floatx4 acc[2][8];
  for (int a = 0; a < 2; ++a)
    for (int n = 0; n < 8; ++n) acc[a][n] = (floatx4){0.f, 0.f, 0.f, 0.f};

  const int r0 = Mbase + w * 32 + l16;
  for (int ks = 0; ks < 16; ++ks) {
    const int k0 = ks * 32 + quad * 8;
    short8 a0 = pack8(x + (size_t)r0 * 512 + k0);
    short8 a1 = pack8(x + (size_t)(r0 + 16) * 512 + k0);
    for (int n = 0; n < 8; ++n) {
      short8 b = pack8(W + (size_t)(Nbase + n * 16 + l16) * 512 + k0);
      acc[0][n] = mfma_bf16(a0, b, acc[0][n]);
      acc[1][n] = mfma_bf16(a1, b, acc[1][n]);
    }
  }
  for (int tm = 0; tm < 2; ++tm)
    for (int n = 0; n < 8; ++n)
      for (int rr = 0; rr < 4; ++rr) {
        int row = Mbase + w * 32 + tm * 16 + quad * 4 + rr;  // b*T + t
        int col = Nbase + n * 16 + l16;
        int b = row >> 7, t = row & 127;
        unsigned short val = f2bf(acc[tm][n][rr]);
        dst[((size_t)(t * 64 + b) << 9) + col] = val;
        if (z == 1) kbT[((size_t)(t * 512 + col) << 6) + b] = val;  // k^T per t
      }
}

// ---------------- per-step scalar gates + control init ----------------
__global__ __launch_bounds__(256) void gates_kernel(
    const float* __restrict__ x,
    const float* __restrict__ tw, const float* __restrict__ tb,
    const float* __restrict__ ew, const float* __restrict__ eb,
    const float* __restrict__ aw, const float* __restrict__ ab,
    float* __restrict__ gates, float* __restrict__ lossAcc,
    unsigned* __restrict__ ctr) {
  const int t = blockIdx.x, tid = threadIdx.x;
  __shared__ float red[192];
  if (tid < 192) {
    int g = tid >> 6, b = tid & 63;
    const float* wr = (g == 0) ? tw : (g == 1) ? ew : aw;
    float bias = (g == 0) ? tb[0] : (g == 1) ? eb[0] : ab[0];
    const float* xr = x + ((size_t)b * 128 + t) * 512;
    float s = 0.f;
    for (int i = 0; i < 512; i += 4) {
      float4 xv = *reinterpret_cast<const float4*>(xr + i);
      float4 wv = *reinterpret_cast<const float4*>(wr + i);
      s += xv.x * wv.x + xv.y * wv.y + xv.z * wv.z + xv.w * wv.w;
    }
    red[tid] = 1.f / (1.f + expf(-(s + bias)));
  }
  if (tid == 192) lossAcc[t] = 0.f;
  if (tid == 193 && t == 0) *ctr = 0u;
  __syncthreads();
  if (tid < 3) {
    float s = 0.f;
    for (int i = 0; i < 64; ++i) s += red[tid * 64 + i];
    gates[tid * 128 + t] = s * (1.f / 64.f);
  }
}

// ---------------- persistent sequential scan ----------------
__global__ __launch_bounds__(512, 1) void scan_kernel(
    const unsigned short* __restrict__ qb, const unsigned short* __restrict__ kb,
    const unsigned short* __restrict__ vb, const unsigned short* __restrict__ kbT,
    const float* __restrict__ gates, float* lossAcc, unsigned* ctr,
    const float* __restrict__ inW1, const float* __restrict__ inb1,
    const float* __restrict__ inW2, const float* __restrict__ inb2,
    unsigned short* W2T, unsigned short* RcG, unsigned short* hT,
    unsigned short* dout_rm, float* __restrict__ out) {
  // LDS: bf16 weight copies (row-padded +8 elems -> 2-way banks = free),
  // local transposes stride 72 elems (144B) for the same reason.
  __shared__ unsigned short sW1[32 * 520];
  __shared__ unsigned short sW2[32 * 520];
  __shared__ unsigned short sdt[32 * 72];  // dout^T own cols [j-local][i]
  __shared__ unsigned short sdp[32 * 72];  // dpre^T own cols [l-local][i]
  __shared__ unsigned short shl[32 * 72];  // h own cols [l-local][i] (relu mask)
  __shared__ float b1loc[32], b2loc[32], mb1[32], mb2[32];

  const int tid = threadIdx.x, bid = blockIdx.x;
  const int lane = tid & 63, w = tid >> 6;
  const int quad = lane >> 4, l16 = lane & 15;
  const int J = bid * 32;
  const int mt = w & 1, ng = w >> 1;     // D1/D2/state decomposition
  const int mtc = w & 3, ntc = w >> 2;   // phase-C decomposition
  unsigned ep = 0;

  // ---- per-thread register state: masters + momentum, frag-aligned ----
  float w1s[32], m1s[32], w2s[32], m2s[32];
#pragma unroll
  for (int g = 0; g < 8; ++g)
#pragma unroll
    for (int rr = 0; rr < 4; ++rr) {
      const int jl = mt * 16 + quad * 4 + rr;
      const int l = (ng * 8 + g) * 16 + l16;
      const int si = g * 4 + rr;
      const size_t gi = (size_t)(J + jl) * 512 + l;
      float a = inW1[gi]; w1s[si] = a; m1s[si] = 0.f; sW1[jl * 520 + l] = f2bf(a);
      float b = inW2[gi]; w2s[si] = b; m2s[si] = 0.f; sW2[jl * 520 + l] = f2bf(b);
    }
  if (tid < 32) {
    b1loc[tid] = inb1[J + tid]; mb1[tid] = 0.f;
    b2loc[tid] = inb2[J + tid]; mb2[tid] = 0.f;
  }
  __syncthreads();
  {  // initial W2^T publish (parity 0): own 32x32 chunk per l, packed 8B
    const int l = tid;
    unsigned short tmp[32];
#pragma unroll
    for (int c = 0; c < 32; ++c) tmp[c] = sW2[c * 520 + l];
    unsigned short* dstp = W2T + (size_t)l * 512 + J;
#pragma unroll
    for (int s4 = 0; s4 < 8; ++s4) st8_sc(dstp + s4 * 4, pack4(tmp + s4 * 4));
  }

  for (int t = 0; t < 128; ++t) {
    const int par = t & 1, nxt = par ^ 1;
    const float th = gates[t], et = gates[128 + t], al = gates[256 + t];
    const float oma = 1.f - al;
    const unsigned short* qt = qb + ((size_t)t << 15);
    const unsigned short* kt = kb + ((size_t)t << 15);
    const unsigned short* vt = vb + ((size_t)t << 15);
    const unsigned short* ktT = kbT + ((size_t)t << 15);
    unsigned short* hTp = hT + par * 32768;
    const unsigned short* w2tp = W2T + (size_t)par * 262144;
    unsigned short* w2tn = W2T + (size_t)nxt * 262144;

    // ---- Phase A: h = relu([q;k] @ W1^T + b1), own 32 cols ----
    {
      const int row = w * 16 + l16;
      const unsigned short* arow = (row < 64) ? (qt + (size_t)row * 512)
                                              : (kt + (size_t)(row - 64) * 512);
      floatx4 a0 = {0.f,0.f,0.f,0.f}, a1 = {0.f,0.f,0.f,0.f};
#pragma unroll
      for (int half = 0; half < 2; ++half) {
        short8 af[8];
#pragma unroll
        for (int ks = 0; ks < 8; ++ks)
          af[ks] = ldbf8(arow + (half * 8 + ks) * 32 + quad * 8);
#pragma unroll
        for (int ks = 0; ks < 8; ++ks) {
          const int k0 = (half * 8 + ks) * 32 + quad * 8;
          short8 b0 = *reinterpret_cast<const short8*>(&sW1[l16 * 520 + k0]);
          short8 b1f = *reinterpret_cast<const short8*>(&sW1[(16 + l16) * 520 + k0]);
          a0 = mfma_bf16(af[ks], b0, a0);
          a1 = mfma_bf16(af[ks], b1f, a1);
        }
      }
      const float bi0 = b1loc[l16], bi1 = b1loc[16 + l16];
#pragma unroll
      for (int rr = 0; rr < 4; ++rr) {
        const int orow = w * 16 + quad * 4 + rr;
        float v0 = fmaxf(a0[rr] + bi0, 0.f);
        float v1 = fmaxf(a1[rr] + bi1, 0.f);
        unsigned short h0 = f2bf(v0), h1 = f2bf(v1);
        st2_sc(RcG + (size_t)orow * 512 + J + l16, h0);
        st2_sc(RcG + (size_t)orow * 512 + J + 16 + l16, h1);
        if (orow >= 64) {
          const int i = orow - 64;
          st2_sc(hTp + (size_t)(J + l16) * 64 + i, h0);
          st2_sc(hTp + (size_t)(J + 16 + l16) * 64 + i, h1);
          shl[l16 * 72 + i] = h0;
          shl[(16 + l16) * 72 + i] = h1;
        }
      }
    }
    gridbar(ctr, ep);

    // ---- Phase B: out/dout = h @ W2^T + b2, own 32 cols ----
    {
      const int row = w * 16 + l16;
      const unsigned short* arow = RcG + (size_t)row * 512;
      floatx4 a0 = {0.f,0.f,0.f,0.f}, a1 = {0.f,0.f,0.f,0.f};
#pragma unroll
      for (int half = 0; half < 2; ++half) {
        short8 af[8];
#pragma unroll
        for (int ks = 0; ks < 8; ++ks)
          af[ks] = ld16_sc(arow + (half * 8 + ks) * 32 + quad * 8);
#pragma unroll
        for (int ks = 0; ks < 8; ++ks) {
          const int k0 = (half * 8 + ks) * 32 + quad * 8;
          short8 b0 = *reinterpret_cast<const short8*>(&sW2[l16 * 520 + k0]);
          short8 b1f = *reinterpret_cast<const short8*>(&sW2[(16 + l16) * 520 + k0]);
          a0 = mfma_bf16(af[ks], b0, a0);
          a1 = mfma_bf16(af[ks], b1f, a1);
        }
      }
      const float bi0 = b2loc[l16], bi1 = b2loc[16 + l16];
      float lossp = 0.f;
#pragma unroll
      for (int rr = 0; rr < 4; ++rr) {
        const int orow = w * 16 + quad * 4 + rr;
        float o0 = a0[rr] + bi0, o1 = a1[rr] + bi1;
        if (orow < 64) {
          size_t o = ((size_t)orow * 128 + t) * 512;
          out[o + J + l16] = o0;
          out[o + J + 16 + l16] = o1;
          out[4194304 + o + J + l16] = o0;
          out[4194304 + o + J + 16 + l16] = o1;
        } else {
          const int i = orow - 64;
          float d0 = o0 - bf2f(vt[(size_t)i * 512 + J + l16]);
          float d1 = o1 - bf2f(vt[(size_t)i * 512 + J + 16 + l16]);
          lossp += d0 * d0 + d1 * d1;
          unsigned short q0 = f2bf(6.103515625e-5f * d0);  // (2/N), N=32768
          unsigned short q1 = f2bf(6.103515625e-5f * d1);
          st2_sc(dout_rm + (size_t)i * 512 + J + l16, q0);
          st2_sc(dout_rm + (size_t)i * 512 + J + 16 + l16, q1);
          sdt[l16 * 72 + i] = q0;
          sdt[(16 + l16) * 72 + i] = q1;
        }
      }
      if (w >= 4) {
        for (int off = 32; off > 0; off >>= 1) lossp += __shfl_down(lossp, off);
        if (lane == 0)
          __hip_atomic_fetch_add(lossAcc + t, lossp, __ATOMIC_RELAXED, SC_AGENT);
      }
    }
    gridbar(ctr, ep);

    const float loss =
        __hip_atomic_load(lossAcc + t, __ATOMIC_RELAXED, SC_AGENT) * (1.f / 32768.f);
    const float pt = (loss >= 1e-10f && loss <= 1e10f) ? 1.f : 0.f;

    // ---- Phase C: dpre[:, own l] = relu' * (dout @ W2T_own^T) ----
    {
      const unsigned short* arow = dout_rm + (size_t)(mtc * 16 + l16) * 512;
      const unsigned short* brow = w2tp + (size_t)(J + ntc * 16 + l16) * 512;
      floatx4 acc = {0.f,0.f,0.f,0.f};
#pragma unroll
      for (int half = 0; half < 2; ++half) {
        short8 afr[8], bfr[8];
#pragma unroll
        for (int ks = 0; ks < 8; ++ks) {
          const int k0 = (half * 8 + ks) * 32 + quad * 8;
          afr[ks] = ld16_sc(arow + k0);
          bfr[ks] = ld16_sc(brow + k0);
        }
#pragma unroll
        for (int ks = 0; ks < 8; ++ks) acc = mfma_bf16(afr[ks], bfr[ks], acc);
      }
#pragma unroll
      for (int rr = 0; rr < 4; ++rr) {
        const int i = mtc * 16 + quad * 4 + rr;
        const int jl = ntc * 16 + l16;
        unsigned short hb = shl[jl * 72 + i];
        sdp[jl * 72 + i] = (hb != 0) ? f2bf(acc[rr]) : (unsigned short)0;
      }
    }
    __syncthreads();

    // ---- Phase D1: gW1 own rows (K=64) + register update ----
    {
      floatx4 acc1[8];
#pragma unroll
      for (int g = 0; g < 8; ++g) acc1[g] = (floatx4){0.f,0.f,0.f,0.f};
#pragma unroll
      for (int half = 0; half < 2; ++half) {
        short8 bfr[2][4];
#pragma unroll
        for (int ks = 0; ks < 2; ++ks)
#pragma unroll
          for (int g = 0; g < 4; ++g) {
            const int l = (ng * 8 + half * 4 + g) * 16 + l16;
            bfr[ks][g] = ldbf8(ktT + (size_t)l * 64 + ks * 32 + quad * 8);
          }
#pragma unroll
        for (int ks = 0; ks < 2; ++ks) {
          short8 af = *reinterpret_cast<const short8*>(
              &sdp[(mt * 16 + l16) * 72 + ks * 32 + quad * 8]);
#pragma unroll
          for (int g = 0; g < 4; ++g)
            acc1[half * 4 + g] = mfma_bf16(af, bfr[ks][g], acc1[half * 4 + g]);
        }
      }
#pragma unroll
      for (int g = 0; g < 8; ++g)
#pragma unroll
        for (int rr = 0; rr < 4; ++rr) {
          const int jl = mt * 16 + quad * 4 + rr;
          const int l = (ng * 8 + g) * 16 + l16;
          const int si = g * 4 + rr;
          float m = et * m1s[si] - th * (pt * acc1[g][rr]);
          float wv = oma * w1s[si] + m;
          m1s[si] = m; w1s[si] = wv;
          sW1[jl * 520 + l] = f2bf(wv);
        }
      if (tid < 32) {
        float s = 0.f;
        for (int i = 0; i < 64; ++i) s += bf2f(sdp[tid * 72 + i]);
        float m = et * mb1[tid] - th * (pt * s);
        float bv = oma * b1loc[tid] + m;
        mb1[tid] = m; b1loc[tid] = bv;
      }
    }

    // ---- Phase D2: gW2 own rows (K=64) + register update ----
    {
      floatx4 acc2[8];
#pragma unroll
      for (int g = 0; g < 8; ++g) acc2[g] = (floatx4){0.f,0.f,0.f,0.f};
#pragma unroll
      for (int half = 0; half < 2; ++half) {
        short8 bfr[2][4];
#pragma unroll
        for (int ks = 0; ks < 2; ++ks)
#pragma unroll
          for (int g = 0; g < 4; ++g) {
            const int l = (ng * 8 + half * 4 + g) * 16 + l16;
            bfr[ks][g] = ld16_sc(hTp + (size_t)l * 64 + ks * 32 + quad * 8);
          }
#pragma unroll
        for (int ks = 0; ks < 2; ++ks) {
          short8 af = *reinterpret_cast<const short8*>(
              &sdt[(mt * 16 + l16) * 72 + ks * 32 + quad * 8]);
#pragma unroll
          for (int g = 0; g < 4; ++g)
            acc2[half * 4 + g] = mfma_bf16(af, bfr[ks][g], acc2[half * 4 + g]);
        }
      }
#pragma unroll
      for (int g = 0; g < 8; ++g)
#pragma unroll
        for (int rr = 0; rr < 4; ++rr) {
          const int jl = mt * 16 + quad * 4 + rr;
          const int l = (ng * 8 + g) * 16 + l16;
          const int si = g * 4 + rr;
          float m = et * m2s[si] - th * (pt * acc2[g][rr]);
          float wv = oma * w2s[si] + m;
          m2s[si] = m; w2s[si] = wv;
          sW2[jl * 520 + l] = f2bf(wv);
        }
      if (tid < 32) {
        float s = 0.f;
        for (int i = 0; i < 64; ++i) s += bf2f(sdt[tid * 72 + i]);
        float m = et * mb2[tid] - th * (pt * s);
        float bv = oma * b2loc[tid] + m;
        mb2[tid] = m; b2loc[tid] = bv;
      }
    }
    __syncthreads();

    // ---- publish W2^T (next parity) from updated LDS copy ----
    {
      const int l = tid;
      unsigned short tmp[32];
#pragma unroll
      for (int c = 0; c < 32; ++c) tmp[c] = sW2[c * 520 + l];
      unsigned short* dstp = w2tn + (size_t)l * 512 + J;
#pragma unroll
      for (int s4 = 0; s4 < 8; ++s4) st8_sc(dstp + s4 * 4, pack4(tmp + s4 * 4));
    }
    __syncthreads();
  }
}

extern "C" void kernel_launch(void* const* d_in, const int* in_sizes, int n_in,
                              void* d_out, int out_size, void* d_ws, size_t ws_size,
                              hipStream_t stream) {
  const float* x  = (const float*)d_in[0];
  const float* WQ = (const float*)d_in[1];
  const float* WK = (const float*)d_in[2];
  const float* WV = (const float*)d_in[3];
  const float* tw = (const float*)d_in[4];
  const float* tb = (const float*)d_in[5];
  const float* ew = (const float*)d_in[6];
  const float* eb = (const float*)d_in[7];
  const float* aw = (const float*)d_in[8];
  const float* ab = (const float*)d_in[9];
  const float* W1 = (const float*)d_in[10];
  const float* b1 = (const float*)d_in[11];
  const float* W2 = (const float*)d_in[12];
  const float* b2 = (const float*)d_in[13];
  float* out = (float*)d_out;

  char* ws = (char*)d_ws;
  size_t off = 0;
  auto alloc = [&](size_t b) {
    char* p = ws + off;
    off = (off + b + 255) & ~(size_t)255;
    return p;
  };
  unsigned short* qb   = (unsigned short*)alloc(8388608);
  unsigned short* kb   = (unsigned short*)alloc(8388608);
  unsigned short* vb   = (unsigned short*)alloc(8388608);
  unsigned short* kbT  = (unsigned short*)alloc(8388608);
  float* gates   = (float*)alloc(1536);
  float* lossAcc = (float*)alloc(512);
  unsigned* ctr  = (unsigned*)alloc(256);
  unsigned short* W2T  = (unsigned short*)alloc(1048576);  // 2 parities
  unsigned short* RcG  = (unsigned short*)alloc(131072);   // [128][512]
  unsigned short* hT   = (unsigned short*)alloc(131072);   // 2 parities [512][64]
  unsigned short* dout_rm = (unsigned short*)alloc(65536); // [64][512]
  (void)in_sizes; (void)n_in; (void)out_size; (void)ws_size;

  qkv_kernel<<<dim3(64, 4, 3), 256, 0, stream>>>(x, WQ, WK, WV, qb, kb, vb, kbT);
  gates_kernel<<<dim3(128), 256, 0, stream>>>(x, tw, tb, ew, eb, aw, ab,
                                              gates, lossAcc, ctr);
  scan_kernel<<<dim3(GBLK), 512, 0, stream>>>(
      qb, kb, vb, kbT, gates, lossAcc, ctr,
      W1, b1, W2, b2,
      W2T, RcG, hT, dout_rm, out);
}

// Round 5
// 6699.381 us; speedup vs baseline: 1.4829x; 1.1577x over previous
//
#include <hip/hip_runtime.h>
#include <stdint.h>

// B=64, T=128, D=512. Persistent scan: 16 blocks x 512 threads, column-
// partitioned (32 rows of W1/W2 per block), 2 grid barriers/step.
// R5 = R4 + fix: Phase-B out store now covers all 16 rows/wave (2x8).
// Cross-block stores are coalesced 16B/lane global_store_dwordx4 sc0 sc1
// staged through LDS; W2T transpose maintained in LDS during the update.

typedef __attribute__((ext_vector_type(8))) short short8;
typedef __attribute__((ext_vector_type(4))) float floatx4;

#define GBLK 16
#define SC_AGENT __HIP_MEMORY_SCOPE_AGENT

__device__ inline floatx4 mfma_bf16(short8 a, short8 b, floatx4 c) {
  return __builtin_amdgcn_mfma_f32_16x16x32_bf16(a, b, c, 0, 0, 0);
}
__device__ inline unsigned short f2bf(float f) {
  unsigned u = __float_as_uint(f);
  u += 0x7fffu + ((u >> 16) & 1u);
  return (unsigned short)(u >> 16);
}
__device__ inline float bf2f(unsigned short h) {
  return __uint_as_float(((unsigned)h) << 16);
}
__device__ inline short8 ldbf8(const unsigned short* p) {
  return *reinterpret_cast<const short8*>(p);
}
// coalesced 16B device-coherent store (write-through to coherence point)
__device__ inline void stg16_sc(unsigned short* p, short8 v) {
  asm volatile("global_store_dwordx4 %0, %1, off sc0 sc1"
               :: "v"(p), "v"(v) : "memory");
}
__device__ inline void vmwait() {
  asm volatile("s_waitcnt vmcnt(0)" ::: "memory");
}
// device-coherent 16B load as 2x8B relaxed atomics (compiler-tracked vmcnt)
__device__ inline short8 ld16_sc(const unsigned short* p) {
  union { unsigned long long u[2]; short8 s; } c;
  c.u[0] = __hip_atomic_load(reinterpret_cast<const unsigned long long*>(p),
                             __ATOMIC_RELAXED, SC_AGENT);
  c.u[1] = __hip_atomic_load(reinterpret_cast<const unsigned long long*>(p + 4),
                             __ATOMIC_RELAXED, SC_AGENT);
  return c.s;
}
__device__ inline short8 pack8(const float* p) {
  float4 a = *reinterpret_cast<const float4*>(p);
  float4 b = *reinterpret_cast<const float4*>(p + 4);
  short8 r;
  r[0] = (short)f2bf(a.x); r[1] = (short)f2bf(a.y);
  r[2] = (short)f2bf(a.z); r[3] = (short)f2bf(a.w);
  r[4] = (short)f2bf(b.x); r[5] = (short)f2bf(b.y);
  r[6] = (short)f2bf(b.z); r[7] = (short)f2bf(b.w);
  return r;
}

// Grid barrier. vmwait drains each wave's asm stores before s_barrier;
// arrival/spins are relaxed agent atomics. No cache-wide maintenance.
__device__ inline void gridbar(unsigned* ctr, unsigned& ep) {
  vmwait();
  __syncthreads();
  if (threadIdx.x == 0) {
    __hip_atomic_fetch_add(ctr, 1u, __ATOMIC_RELAXED, SC_AGENT);
    const unsigned target = (ep + 1u) * GBLK;
    while (__hip_atomic_load(ctr, __ATOMIC_RELAXED, SC_AGENT) < target)
      __builtin_amdgcn_s_sleep(1);
  }
  ++ep;
  __syncthreads();
}

// ---------------- q/k/v projections (bf16 out) ----------------
__global__ __launch_bounds__(256) void qkv_kernel(
    const float* __restrict__ x, const float* __restrict__ WQ,
    const float* __restrict__ WK, const float* __restrict__ WV,
    unsigned short* __restrict__ qb, unsigned short* __restrict__ kb,
    unsigned short* __restrict__ vb, unsigned short* __restrict__ kbT) {
  const int tid = threadIdx.x;
  const int lane = tid & 63, w = tid >> 6;
  const int quad = lane >> 4, l16 = lane & 15;
  const int Mbase = blockIdx.x * 128;
  const int Nbase = blockIdx.y * 128;
  const int z = blockIdx.z;
  const float* W = (z == 0) ? WQ : (z == 1) ? WK : WV;
  unsigned short* dst = (z == 0) ? qb : (z == 1) ? kb : vb;

  floatx4 acc[2][8];
  for (int a = 0; a < 2; ++a)
    for (int n = 0; n < 8; ++n) acc[a][n] = (floatx4){0.f, 0.f, 0.f, 0.f};

  const int r0 = Mbase + w * 32 + l16;
  for (int ks = 0; ks < 16; ++ks) {
    const int k0 = ks * 32 + quad * 8;
    short8 a0 = pack8(x + (size_t)r0 * 512 + k0);
    short8 a1 = pack8(x + (size_t)(r0 + 16) * 512 + k0);
    for (int n = 0; n < 8; ++n) {
      short8 b = pack8(W + (size_t)(Nbase + n * 16 + l16) * 512 + k0);
      acc[0][n] = mfma_bf16(a0, b, acc[0][n]);
      acc[1][n] = mfma_bf16(a1, b, acc[1][n]);
    }
  }
  for (int tm = 0; tm < 2; ++tm)
    for (int n = 0; n < 8; ++n)
      for (int rr = 0; rr < 4; ++rr) {
        int row = Mbase + w * 32 + tm * 16 + quad * 4 + rr;  // b*T + t
        int col = Nbase + n * 16 + l16;
        int b = row >> 7, t = row & 127;
        unsigned short val = f2bf(acc[tm][n][rr]);
        dst[((size_t)(t * 64 + b) << 9) + col] = val;
        if (z == 1) kbT[((size_t)(t * 512 + col) << 6) + b] = val;  // k^T per t
      }
}

// ---------------- per-step scalar gates + control init ----------------
__global__ __launch_bounds__(256) void gates_kernel(
    const float* __restrict__ x,
    const float* __restrict__ tw, const float* __restrict__ tb,
    const float* __restrict__ ew, const float* __restrict__ eb,
    const float* __restrict__ aw, const float* __restrict__ ab,
    float* __restrict__ gates, float* __restrict__ lossAcc,
    unsigned* __restrict__ ctr) {
  const int t = blockIdx.x, tid = threadIdx.x;
  __shared__ float red[192];
  if (tid < 192) {
    int g = tid >> 6, b = tid & 63;
    const float* wr = (g == 0) ? tw : (g == 1) ? ew : aw;
    float bias = (g == 0) ? tb[0] : (g == 1) ? eb[0] : ab[0];
    const float* xr = x + ((size_t)b * 128 + t) * 512;
    float s = 0.f;
    for (int i = 0; i < 512; i += 4) {
      float4 xv = *reinterpret_cast<const float4*>(xr + i);
      float4 wv = *reinterpret_cast<const float4*>(wr + i);
      s += xv.x * wv.x + xv.y * wv.y + xv.z * wv.z + xv.w * wv.w;
    }
    red[tid] = 1.f / (1.f + expf(-(s + bias)));
  }
  if (tid == 192) lossAcc[t] = 0.f;
  if (tid == 193 && t == 0) *ctr = 0u;
  __syncthreads();
  if (tid < 3) {
    float s = 0.f;
    for (int i = 0; i < 64; ++i) s += red[tid * 64 + i];
    gates[tid * 128 + t] = s * (1.f / 64.f);
  }
}

// ---------------- persistent sequential scan ----------------
__global__ __launch_bounds__(512, 2) void scan_kernel(
    const unsigned short* __restrict__ qb, const unsigned short* __restrict__ kb,
    const unsigned short* __restrict__ vb, const unsigned short* __restrict__ kbT,
    const float* __restrict__ gates, float* lossAcc, unsigned* ctr,
    const float* __restrict__ inW1, const float* __restrict__ inb1,
    const float* __restrict__ inW2, const float* __restrict__ inb2,
    unsigned short* W2T, unsigned short* RcG, unsigned short* hT,
    unsigned short* dout_rm, float* __restrict__ out) {
  __shared__ unsigned short sW1[32 * 520];   // bf16 W1 own rows, row-major
  __shared__ unsigned short sW2[32 * 520];   // bf16 W2 own rows, row-major
  __shared__ unsigned short sWT[512 * 40];   // bf16 W2^T own cols [l][jl]
  __shared__ unsigned short shl[32 * 72];    // h own cols [jl][i] (mask + hT stage)
  __shared__ unsigned short sdt[32 * 72];    // dout^T own cols [jl][i]
  __shared__ unsigned short sdp[32 * 72];    // dpre^T own cols [jl][i]
  __shared__ unsigned short sStA[128 * 32];  // h staging [row][colLocal]
  __shared__ unsigned short sDR[64 * 32];    // dout staging [i][colLocal]
  __shared__ float sOutF[64 * 32];           // out staging fp32
  __shared__ float b1loc[32], b2loc[32], mb1[32], mb2[32];

  const int tid = threadIdx.x, bid = blockIdx.x;
  const int lane = tid & 63, w = tid >> 6;
  const int quad = lane >> 4, l16 = lane & 15;
  const int J = bid * 32;
  const int mt = w & 1, ng = w >> 1;     // D1/D2/state decomposition
  const int mtc = w & 3, ntc = w >> 2;   // phase-C decomposition
  unsigned ep = 0;

  // ---- per-thread register state: masters + momentum, frag-aligned ----
  float w1s[32], m1s[32], w2s[32], m2s[32];
#pragma unroll
  for (int g = 0; g < 8; ++g) {
    unsigned short tp[4];
#pragma unroll
    for (int rr = 0; rr < 4; ++rr) {
      const int jl = mt * 16 + quad * 4 + rr;
      const int l = (ng * 8 + g) * 16 + l16;
      const int si = g * 4 + rr;
      const size_t gi = (size_t)(J + jl) * 512 + l;
      float a = inW1[gi]; w1s[si] = a; m1s[si] = 0.f; sW1[jl * 520 + l] = f2bf(a);
      float b = inW2[gi]; w2s[si] = b; m2s[si] = 0.f;
      unsigned short bb = f2bf(b);
      sW2[jl * 520 + l] = bb; tp[rr] = bb;
    }
    const int l = (ng * 8 + g) * 16 + l16;
    *reinterpret_cast<unsigned long long*>(&sWT[l * 40 + mt * 16 + quad * 4]) =
        (unsigned long long)tp[0] | ((unsigned long long)tp[1] << 16) |
        ((unsigned long long)tp[2] << 32) | ((unsigned long long)tp[3] << 48);
  }
  if (tid < 32) {
    b1loc[tid] = inb1[J + tid]; mb1[tid] = 0.f;
    b2loc[tid] = inb2[J + tid]; mb2[tid] = 0.f;
  }
  __syncthreads();
  {  // initial W2^T publish (parity 0): coalesced 16 rows/instr
#pragma unroll
    for (int ii = 0; ii < 4; ++ii) {
      const int r = w * 64 + ii * 16 + (lane >> 2), c = lane & 3;
      short8 v = *reinterpret_cast<const short8*>(&sWT[r * 40 + c * 8]);
      stg16_sc(W2T + (size_t)r * 512 + J + c * 8, v);
    }
  }

  for (int t = 0; t < 128; ++t) {
    const int par = t & 1, nxt = par ^ 1;
    const float th = gates[t], et = gates[128 + t], al = gates[256 + t];
    const float oma = 1.f - al;
    const unsigned short* qt = qb + ((size_t)t << 15);
    const unsigned short* kt = kb + ((size_t)t << 15);
    const unsigned short* vt = vb + ((size_t)t << 15);
    const unsigned short* ktT = kbT + ((size_t)t << 15);
    unsigned short* hTp = hT + par * 32768;
    const unsigned short* w2tp = W2T + (size_t)par * 262144;
    unsigned short* w2tn = W2T + (size_t)nxt * 262144;

    // ---- Phase A: h = relu([q;k] @ W1^T + b1), own 32 cols ----
    {
      const int row = w * 16 + l16;
      const unsigned short* arow = (row < 64) ? (qt + (size_t)row * 512)
                                              : (kt + (size_t)(row - 64) * 512);
      floatx4 a0 = {0.f,0.f,0.f,0.f}, a1 = {0.f,0.f,0.f,0.f};
#pragma unroll
      for (int half = 0; half < 2; ++half) {
        short8 af[8];
#pragma unroll
        for (int ks = 0; ks < 8; ++ks)
          af[ks] = ldbf8(arow + (half * 8 + ks) * 32 + quad * 8);
#pragma unroll
        for (int ks = 0; ks < 8; ++ks) {
          const int k0 = (half * 8 + ks) * 32 + quad * 8;
          short8 b0 = *reinterpret_cast<const short8*>(&sW1[l16 * 520 + k0]);
          short8 b1f = *reinterpret_cast<const short8*>(&sW1[(16 + l16) * 520 + k0]);
          a0 = mfma_bf16(af[ks], b0, a0);
          a1 = mfma_bf16(af[ks], b1f, a1);
        }
      }
      const float bi0 = b1loc[l16], bi1 = b1loc[16 + l16];
#pragma unroll
      for (int rr = 0; rr < 4; ++rr) {
        const int orow = w * 16 + quad * 4 + rr;
        float v0 = fmaxf(a0[rr] + bi0, 0.f);
        float v1 = fmaxf(a1[rr] + bi1, 0.f);
        unsigned short h0 = f2bf(v0), h1 = f2bf(v1);
        sStA[orow * 32 + l16] = h0;
        sStA[orow * 32 + 16 + l16] = h1;
        if (orow >= 64) {
          const int i = orow - 64;
          shl[l16 * 72 + i] = h0;
          shl[(16 + l16) * 72 + i] = h1;
        }
      }
      __syncthreads();
      // Rc store: each wave stores its own 16 rows, 16B/lane
      {
        const int r = w * 16 + (lane >> 2), c = lane & 3;
        short8 v = *reinterpret_cast<const short8*>(&sStA[r * 32 + c * 8]);
        stg16_sc(RcG + (size_t)r * 512 + J + c * 8, v);
      }
      // hT store: waves 0-3 store shl rows (8 rows x 128B per wave)
      if (w < 4) {
        const int r = w * 8 + (lane >> 3), c = lane & 7;
        short8 v = *reinterpret_cast<const short8*>(&shl[r * 72 + c * 8]);
        stg16_sc(hTp + (size_t)(J + r) * 64 + c * 8, v);
      }
    }
    gridbar(ctr, ep);

    // ---- Phase B: out/dout = h @ W2^T + b2, own 32 cols ----
    {
      const int row = w * 16 + l16;
      const unsigned short* arow = RcG + (size_t)row * 512;
      floatx4 a0 = {0.f,0.f,0.f,0.f}, a1 = {0.f,0.f,0.f,0.f};
#pragma unroll
      for (int half = 0; half < 2; ++half) {
        short8 af[8];
#pragma unroll
        for (int ks = 0; ks < 8; ++ks)
          af[ks] = ld16_sc(arow + (half * 8 + ks) * 32 + quad * 8);
#pragma unroll
        for (int ks = 0; ks < 8; ++ks) {
          const int k0 = (half * 8 + ks) * 32 + quad * 8;
          short8 b0 = *reinterpret_cast<const short8*>(&sW2[l16 * 520 + k0]);
          short8 b1f = *reinterpret_cast<const short8*>(&sW2[(16 + l16) * 520 + k0]);
          a0 = mfma_bf16(af[ks], b0, a0);
          a1 = mfma_bf16(af[ks], b1f, a1);
        }
      }
      const float bi0 = b2loc[l16], bi1 = b2loc[16 + l16];
      float lossp = 0.f;
#pragma unroll
      for (int rr = 0; rr < 4; ++rr) {
        const int orow = w * 16 + quad * 4 + rr;
        float o0 = a0[rr] + bi0, o1 = a1[rr] + bi1;
        if (orow < 64) {
          sOutF[orow * 32 + l16] = o0;
          sOutF[orow * 32 + 16 + l16] = o1;
        } else {
          const int i = orow - 64;
          float d0 = o0 - bf2f(vt[(size_t)i * 512 + J + l16]);
          float d1 = o1 - bf2f(vt[(size_t)i * 512 + J + 16 + l16]);
          lossp += d0 * d0 + d1 * d1;
          unsigned short q0 = f2bf(6.103515625e-5f * d0);  // (2/N), N=32768
          unsigned short q1 = f2bf(6.103515625e-5f * d1);
          sDR[i * 32 + l16] = q0;
          sDR[i * 32 + 16 + l16] = q1;
          sdt[l16 * 72 + i] = q0;
          sdt[(16 + l16) * 72 + i] = q1;
        }
      }
      if (w < 4) {  // out store: own 16 rows (2x8) x 128B, 2 copies (plain fp32)
#pragma unroll
        for (int ii = 0; ii < 2; ++ii) {
          const int r = w * 16 + ii * 8 + (lane >> 3), c = lane & 7;
          float4 v = *reinterpret_cast<const float4*>(&sOutF[r * 32 + c * 4]);
          float* o0p = out + ((size_t)r * 128 + t) * 512 + J + c * 4;
          *reinterpret_cast<float4*>(o0p) = v;
          *reinterpret_cast<float4*>(o0p + 4194304) = v;
        }
      } else {      // dout store: own 16 rows x 64B, 16B/lane
        const int r = (w - 4) * 16 + (lane >> 2), c = lane & 3;
        short8 v = *reinterpret_cast<const short8*>(&sDR[r * 32 + c * 8]);
        stg16_sc(dout_rm + (size_t)r * 512 + J + c * 8, v);
      }
      if (w >= 4) {
        for (int off = 32; off > 0; off >>= 1) lossp += __shfl_down(lossp, off);
        if (lane == 0)
          __hip_atomic_fetch_add(lossAcc + t, lossp, __ATOMIC_RELAXED, SC_AGENT);
      }
    }
    gridbar(ctr, ep);

    const float loss =
        __hip_atomic_load(lossAcc + t, __ATOMIC_RELAXED, SC_AGENT) * (1.f / 32768.f);
    const float pt = (loss >= 1e-10f && loss <= 1e10f) ? 1.f : 0.f;

    // ---- Phase C: dpre[:, own l] = relu' * (dout @ W2T_own^T) ----
    {
      const unsigned short* arow = dout_rm + (size_t)(mtc * 16 + l16) * 512;
      const unsigned short* brow = w2tp + (size_t)(J + ntc * 16 + l16) * 512;
      floatx4 acc = {0.f,0.f,0.f,0.f};
#pragma unroll
      for (int half = 0; half < 2; ++half) {
        short8 afr[8], bfr[8];
#pragma unroll
        for (int ks = 0; ks < 8; ++ks) {
          const int k0 = (half * 8 + ks) * 32 + quad * 8;
          afr[ks] = ld16_sc(arow + k0);
          bfr[ks] = ld16_sc(brow + k0);
        }
#pragma unroll
        for (int ks = 0; ks < 8; ++ks) acc = mfma_bf16(afr[ks], bfr[ks], acc);
      }
#pragma unroll
      for (int rr = 0; rr < 4; ++rr) {
        const int i = mtc * 16 + quad * 4 + rr;
        const int jl = ntc * 16 + l16;
        unsigned short hb = shl[jl * 72 + i];
        sdp[jl * 72 + i] = (hb != 0) ? f2bf(acc[rr]) : (unsigned short)0;
      }
    }
    __syncthreads();

    // ---- Phase D1: gW1 own rows (K=64) + register update ----
    {
      floatx4 acc1[8];
#pragma unroll
      for (int g = 0; g < 8; ++g) acc1[g] = (floatx4){0.f,0.f,0.f,0.f};
#pragma unroll
      for (int half = 0; half < 2; ++half) {
        short8 bfr[2][4];
#pragma unroll
        for (int ks = 0; ks < 2; ++ks)
#pragma unroll
          for (int g = 0; g < 4; ++g) {
            const int l = (ng * 8 + half * 4 + g) * 16 + l16;
            bfr[ks][g] = ldbf8(ktT + (size_t)l * 64 + ks * 32 + quad * 8);
          }
#pragma unroll
        for (int ks = 0; ks < 2; ++ks) {
          short8 af = *reinterpret_cast<const short8*>(
              &sdp[(mt * 16 + l16) * 72 + ks * 32 + quad * 8]);
#pragma unroll
          for (int g = 0; g < 4; ++g)
            acc1[half * 4 + g] = mfma_bf16(af, bfr[ks][g], acc1[half * 4 + g]);
        }
      }
#pragma unroll
      for (int g = 0; g < 8; ++g)
#pragma unroll
        for (int rr = 0; rr < 4; ++rr) {
          const int jl = mt * 16 + quad * 4 + rr;
          const int l = (ng * 8 + g) * 16 + l16;
          const int si = g * 4 + rr;
          float m = et * m1s[si] - th * (pt * acc1[g][rr]);
          float wv = oma * w1s[si] + m;
          m1s[si] = m; w1s[si] = wv;
          sW1[jl * 520 + l] = f2bf(wv);
        }
      if (tid < 32) {
        float s = 0.f;
        for (int i = 0; i < 64; ++i) s += bf2f(sdp[tid * 72 + i]);
        float m = et * mb1[tid] - th * (pt * s);
        float bv = oma * b1loc[tid] + m;
        mb1[tid] = m; b1loc[tid] = bv;
      }
    }

    // ---- Phase D2: gW2 own rows (K=64) + register update + sWT upkeep ----
    {
      floatx4 acc2[8];
#pragma unroll
      for (int g = 0; g < 8; ++g) acc2[g] = (floatx4){0.f,0.f,0.f,0.f};
#pragma unroll
      for (int half = 0; half < 2; ++half) {
        short8 bfr[2][4];
#pragma unroll
        for (int ks = 0; ks < 2; ++ks)
#pragma unroll
          for (int g = 0; g < 4; ++g) {
            const int l = (ng * 8 + half * 4 + g) * 16 + l16;
            bfr[ks][g] = ld16_sc(hTp + (size_t)l * 64 + ks * 32 + quad * 8);
          }
#pragma unroll
        for (int ks = 0; ks < 2; ++ks) {
          short8 af = *reinterpret_cast<const short8*>(
              &sdt[(mt * 16 + l16) * 72 + ks * 32 + quad * 8]);
#pragma unroll
          for (int g = 0; g < 4; ++g)
            acc2[half * 4 + g] = mfma_bf16(af, bfr[ks][g], acc2[half * 4 + g]);
        }
      }
#pragma unroll
      for (int g = 0; g < 8; ++g) {
        unsigned short tp[4];
#pragma unroll
        for (int rr = 0; rr < 4; ++rr) {
          const int jl = mt * 16 + quad * 4 + rr;
          const int l = (ng * 8 + g) * 16 + l16;
          const int si = g * 4 + rr;
          float m = et * m2s[si] - th * (pt * acc2[g][rr]);
          float wv = oma * w2s[si] + m;
          m2s[si] = m; w2s[si] = wv;
          unsigned short bb = f2bf(wv);
          sW2[jl * 520 + l] = bb; tp[rr] = bb;
        }
        const int l = (ng * 8 + g) * 16 + l16;
        *reinterpret_cast<unsigned long long*>(&sWT[l * 40 + mt * 16 + quad * 4]) =
            (unsigned long long)tp[0] | ((unsigned long long)tp[1] << 16) |
            ((unsigned long long)tp[2] << 32) | ((unsigned long long)tp[3] << 48);
      }
      if (tid < 32) {
        float s = 0.f;
        for (int i = 0; i < 64; ++i) s += bf2f(sdt[tid * 72 + i]);
        float m = et * mb2[tid] - th * (pt * s);
        float bv = oma * b2loc[tid] + m;
        mb2[tid] = m; b2loc[tid] = bv;
      }
    }
    __syncthreads();

    // ---- publish W2^T (next parity) from sWT, coalesced 16B/lane ----
    {
#pragma unroll
      for (int ii = 0; ii < 4; ++ii) {
        const int r = w * 64 + ii * 16 + (lane >> 2), c = lane & 3;
        short8 v = *reinterpret_cast<const short8*>(&sWT[r * 40 + c * 8]);
        stg16_sc(w2tn + (size_t)r * 512 + J + c * 8, v);
      }
    }
    __syncthreads();
  }
  vmwait();
}

extern "C" void kernel_launch(void* const* d_in, const int* in_sizes, int n_in,
                              void* d_out, int out_size, void* d_ws, size_t ws_size,
                              hipStream_t stream) {
  const float* x  = (const float*)d_in[0];
  const float* WQ = (const float*)d_in[1];
  const float* WK = (const float*)d_in[2];
  const float* WV = (const float*)d_in[3];
  const float* tw = (const float*)d_in[4];
  const float* tb = (const float*)d_in[5];
  const float* ew = (const float*)d_in[6];
  const float* eb = (const float*)d_in[7];
  const float* aw = (const float*)d_in[8];
  const float* ab = (const float*)d_in[9];
  const float* W1 = (const float*)d_in[10];
  const float* b1 = (const float*)d_in[11];
  const float* W2 = (const float*)d_in[12];
  const float* b2 = (const float*)d_in[13];
  float* out = (float*)d_out;

  char* ws = (char*)d_ws;
  size_t off = 0;
  auto alloc = [&](size_t b) {
    char* p = ws + off;
    off = (off + b + 255) & ~(size_t)255;
    return p;
  };
  unsigned short* qb   = (unsigned short*)alloc(8388608);
  unsigned short* kb   = (unsigned short*)alloc(8388608);
  unsigned short* vb   = (unsigned short*)alloc(8388608);
  unsigned short* kbT  = (unsigned short*)alloc(8388608);
  float* gates   = (float*)alloc(1536);
  float* lossAcc = (float*)alloc(512);
  unsigned* ctr  = (unsigned*)alloc(256);
  unsigned short* W2T  = (unsigned short*)alloc(1048576);  // 2 parities
  unsigned short* RcG  = (unsigned short*)alloc(131072);   // [128][512]
  unsigned short* hT   = (unsigned short*)alloc(131072);   // 2 parities [512][64]
  unsigned short* dout_rm = (unsigned short*)alloc(65536); // [64][512]
  (void)in_sizes; (void)n_in; (void)out_size; (void)ws_size;

  qkv_kernel<<<dim3(64, 4, 3), 256, 0, stream>>>(x, WQ, WK, WV, qb, kb, vb, kbT);
  gates_kernel<<<dim3(128), 256, 0, stream>>>(x, tw, tb, ew, eb, aw, ab,
                                              gates, lossAcc, ctr);
  scan_kernel<<<dim3(GBLK), 512, 0, stream>>>(
      qb, kb, vb, kbT, gates, lossAcc, ctr,
      W1, b1, W2, b2,
      W2T, RcG, hT, dout_rm, out);
}